// Round 1
// baseline (1119.181 us; speedup 1.0000x reference)
//
#include <hip/hip_runtime.h>

#define NB 2
#define SS 2048
#define DMODEL 1024
#define NH 16
#define DHEAD 64
#define NEGV -1e9f

typedef __bf16 bf16;
typedef bf16 bf16x8 __attribute__((ext_vector_type(8)));
typedef float f32x4 __attribute__((ext_vector_type(4)));

static __device__ __forceinline__ f32x4 mfma_16x16x32(bf16x8 a, bf16x8 b, f32x4 c) {
    return __builtin_amdgcn_mfma_f32_16x16x32_bf16(a, b, c, 0, 0, 0);
}

// C[m][n] = sum_k A[m][k] * W[n][k]; A is [M x 1024] fp32, W is [1024 x 1024] fp32.
// mode 0: store bf16 to out[m*1024 + n]           (Q, K projections)
// mode 1: store bf16 to out[((m>>11)*1024+n)*2048 + (m&2047)]   (V transposed: Vt[bh*64+d][s])
// mode 2: store fp32 to out[m*1024 + n]           (output projection)
__global__ __launch_bounds__(256) void gemm_xwt(const float* __restrict__ A,
                                                const float* __restrict__ W,
                                                void* __restrict__ out, int mode)
{
    __shared__ bf16 As[64][40];   // 64 rows x 32 k, +8 pad (stride 80B, 16B-aligned, 2-way banks)
    __shared__ bf16 Ws[64][40];
    const int t  = threadIdx.x;
    const int wv = t >> 6;        // wave id 0..3 -> m-subtile
    const int ln = t & 63;
    const int lo = ln & 15;
    const int qd = ln >> 4;
    const int m0 = blockIdx.y << 6;
    const int n0 = blockIdx.x << 6;
    const int lrow = t >> 2;          // 0..63
    const int lk   = (t & 3) << 3;    // 0,8,16,24

    f32x4 acc[4];
    #pragma unroll
    for (int i = 0; i < 4; ++i) acc[i] = (f32x4){0.f, 0.f, 0.f, 0.f};

    const float* aptr = A + (size_t)(m0 + lrow) * DMODEL + lk;
    const float* wptr = W + (size_t)(n0 + lrow) * DMODEL + lk;

    for (int k0 = 0; k0 < DMODEL; k0 += 32) {
        float4 a0 = *(const float4*)(aptr + k0);
        float4 a1 = *(const float4*)(aptr + k0 + 4);
        float4 w0 = *(const float4*)(wptr + k0);
        float4 w1 = *(const float4*)(wptr + k0 + 4);
        bf16x8 av, wvv;
        av[0]=(bf16)a0.x; av[1]=(bf16)a0.y; av[2]=(bf16)a0.z; av[3]=(bf16)a0.w;
        av[4]=(bf16)a1.x; av[5]=(bf16)a1.y; av[6]=(bf16)a1.z; av[7]=(bf16)a1.w;
        wvv[0]=(bf16)w0.x; wvv[1]=(bf16)w0.y; wvv[2]=(bf16)w0.z; wvv[3]=(bf16)w0.w;
        wvv[4]=(bf16)w1.x; wvv[5]=(bf16)w1.y; wvv[6]=(bf16)w1.z; wvv[7]=(bf16)w1.w;
        *(bf16x8*)&As[lrow][lk] = av;
        *(bf16x8*)&Ws[lrow][lk] = wvv;
        __syncthreads();
        // A-frag: m = lane&15 (within 16-row subtile), k = quad*8 + j
        bf16x8 af = *(const bf16x8*)&As[(wv << 4) + lo][qd << 3];
        #pragma unroll
        for (int tn = 0; tn < 4; ++tn) {
            bf16x8 bfr = *(const bf16x8*)&Ws[(tn << 4) + lo][qd << 3];
            acc[tn] = mfma_16x16x32(af, bfr, acc[tn]);
        }
        __syncthreads();
    }

    #pragma unroll
    for (int tn = 0; tn < 4; ++tn) {
        #pragma unroll
        for (int r = 0; r < 4; ++r) {
            // C/D layout: col = lane&15, row = quad*4 + reg  [m89/m91 verified]
            const int m = m0 + (wv << 4) + (qd << 2) + r;
            const int n = n0 + (tn << 4) + lo;
            const float v = acc[tn][r];
            if (mode == 0) {
                ((bf16*)out)[(size_t)m * DMODEL + n] = (bf16)v;
            } else if (mode == 1) {
                ((bf16*)out)[((size_t)(m >> 11) * 1024 + n) * SS + (m & (SS - 1))] = (bf16)v;
            } else {
                ((float*)out)[(size_t)m * DMODEL + n] = v;
            }
        }
    }
}

// One block per (b, h, 16-row q-tile). 256 threads = 4 waves.
// Pass 1: QK^T via MFMA, online (m,l). Pass 2: recompute, write attn fp32 + P bf16 to LDS.
// Then PV MFMA -> ctx (fp32, [B*S][1024] layout).
__global__ __launch_bounds__(256) void attn_fused(const bf16* __restrict__ Qp,
                                                  const bf16* __restrict__ Kp,
                                                  const bf16* __restrict__ Vt,
                                                  const int* __restrict__ mask,
                                                  float* __restrict__ attn_out,
                                                  float* __restrict__ ctx)
{
    __shared__ bf16 Qs[16][72];          // 16 x 64, +8 pad
    __shared__ bf16 Pb[16][2056];        // 16 x 2048, +8 pad (stride 4112B: 16B-aligned, 2-way banks)
    __shared__ float redM[4][16];
    __shared__ float redL[4][16];

    const int t  = threadIdx.x;
    const int wv = t >> 6, ln = t & 63, lo = ln & 15, qd = ln >> 4;
    const int q0 = blockIdx.x << 4;
    const int h  = blockIdx.y, b = blockIdx.z;
    const int bh = b * NH + h;

    {   // load Q tile 16x64 bf16
        const int r = t >> 4, c = (t & 15) << 2;
        const bf16* src = Qp + (size_t)(b * SS + q0 + r) * DMODEL + h * DHEAD + c;
        Qs[r][c] = src[0]; Qs[r][c+1] = src[1]; Qs[r][c+2] = src[2]; Qs[r][c+3] = src[3];
    }
    __syncthreads();

    const bf16x8 qa0 = *(const bf16x8*)&Qs[lo][qd << 3];
    const bf16x8 qa1 = *(const bf16x8*)&Qs[lo][32 + (qd << 3)];

    float mr[4], lr[4];
    #pragma unroll
    for (int r = 0; r < 4; ++r) { mr[r] = -__builtin_inff(); lr[r] = 0.f; }

    const size_t mask_row0 = (size_t)b * SS + q0 + (qd << 2);

    // ---- pass 1: online max/sum ----
    for (int nt = wv; nt < 128; nt += 4) {
        const int sk = (nt << 4) + lo;
        const bf16* kb = Kp + (size_t)(b * SS + sk) * DMODEL + h * DHEAD + (qd << 3);
        bf16x8 k0v = *(const bf16x8*)kb;
        bf16x8 k1v = *(const bf16x8*)(kb + 32);
        f32x4 a = (f32x4){0.f,0.f,0.f,0.f};
        a = mfma_16x16x32(qa0, k0v, a);
        a = mfma_16x16x32(qa1, k1v, a);
        #pragma unroll
        for (int r = 0; r < 4; ++r) {
            float s = a[r] * 0.125f;
            const int mk = mask[(mask_row0 + r) * SS + sk];
            s = mk ? NEGV : s;
            const float mn = fmaxf(mr[r], s);
            lr[r] = lr[r] * __expf(mr[r] - mn) + __expf(s - mn);
            mr[r] = mn;
        }
    }
    // combine across the 16 lanes of each quad (each quad owns rows qd*4..qd*4+3)
    #pragma unroll
    for (int r = 0; r < 4; ++r) {
        #pragma unroll
        for (int d = 1; d < 16; d <<= 1) {
            const float om = __shfl_xor(mr[r], d);
            const float ol = __shfl_xor(lr[r], d);
            const float mn = fmaxf(mr[r], om);
            lr[r] = lr[r] * __expf(mr[r] - mn) + ol * __expf(om - mn);
            mr[r] = mn;
        }
    }
    if (lo == 0) {
        #pragma unroll
        for (int r = 0; r < 4; ++r) {
            redM[wv][(qd << 2) + r] = mr[r];
            redL[wv][(qd << 2) + r] = lr[r];
        }
    }
    __syncthreads();
    float Mf[4], Li[4];
    #pragma unroll
    for (int r = 0; r < 4; ++r) {
        const int row = (qd << 2) + r;
        const float mf = fmaxf(fmaxf(redM[0][row], redM[1][row]),
                               fmaxf(redM[2][row], redM[3][row]));
        const float lf = redL[0][row] * __expf(redM[0][row] - mf)
                       + redL[1][row] * __expf(redM[1][row] - mf)
                       + redL[2][row] * __expf(redM[2][row] - mf)
                       + redL[3][row] * __expf(redM[3][row] - mf);
        Mf[r] = mf;
        Li[r] = 1.f / lf;
    }

    // ---- pass 2: recompute, normalize, emit ----
    float* aout = attn_out + ((size_t)bh * SS + q0 + (qd << 2)) * SS;
    for (int nt = wv; nt < 128; nt += 4) {
        const int sk = (nt << 4) + lo;
        const bf16* kb = Kp + (size_t)(b * SS + sk) * DMODEL + h * DHEAD + (qd << 3);
        bf16x8 k0v = *(const bf16x8*)kb;
        bf16x8 k1v = *(const bf16x8*)(kb + 32);
        f32x4 a = (f32x4){0.f,0.f,0.f,0.f};
        a = mfma_16x16x32(qa0, k0v, a);
        a = mfma_16x16x32(qa1, k1v, a);
        #pragma unroll
        for (int r = 0; r < 4; ++r) {
            float s = a[r] * 0.125f;
            const int mk = mask[(mask_row0 + r) * SS + sk];
            s = mk ? NEGV : s;
            const float p = __expf(s - Mf[r]) * Li[r];
            aout[(size_t)r * SS + sk] = p;
            Pb[(qd << 2) + r][sk] = (bf16)p;
        }
    }
    __syncthreads();

    // ---- PV: 16x2048 @ 2048x64, wave wv owns d-columns 16*wv..16*wv+15 ----
    f32x4 o = (f32x4){0.f,0.f,0.f,0.f};
    const bf16* vb = Vt + ((size_t)bh * DHEAD + (wv << 4) + lo) * SS + (qd << 3);
    #pragma unroll 4
    for (int kt = 0; kt < 64; ++kt) {
        bf16x8 pa = *(const bf16x8*)&Pb[lo][(kt << 5) + (qd << 3)];
        bf16x8 vvv = *(const bf16x8*)(vb + (kt << 5));
        o = mfma_16x16x32(pa, vvv, o);
    }
    #pragma unroll
    for (int r = 0; r < 4; ++r) {
        ctx[(size_t)(b * SS + q0 + (qd << 2) + r) * DMODEL + h * DHEAD + (wv << 4) + lo] = o[r];
    }
}

// y = LayerNorm(O + residual), one block per row of 1024.
__global__ __launch_bounds__(256) void ln_resid(const float* __restrict__ O,
                                                const float* __restrict__ resid,
                                                float* __restrict__ out)
{
    const int row = blockIdx.x;
    const int t = threadIdx.x;
    const size_t base = (size_t)row * DMODEL + ((size_t)t << 2);
    const float4 o  = *(const float4*)(O + base);
    const float4 rs = *(const float4*)(resid + base);
    const float x0 = o.x + rs.x, x1 = o.y + rs.y, x2 = o.z + rs.z, x3 = o.w + rs.w;
    float s  = x0 + x1 + x2 + x3;
    float ss = x0*x0 + x1*x1 + x2*x2 + x3*x3;
    #pragma unroll
    for (int d = 32; d > 0; d >>= 1) {
        s  += __shfl_xor(s, d);
        ss += __shfl_xor(ss, d);
    }
    __shared__ float ws1[4], ws2[4];
    if ((t & 63) == 0) { ws1[t >> 6] = s; ws2[t >> 6] = ss; }
    __syncthreads();
    s  = ws1[0] + ws1[1] + ws1[2] + ws1[3];
    ss = ws2[0] + ws2[1] + ws2[2] + ws2[3];
    const float mu  = s * (1.f / DMODEL);
    const float var = ss * (1.f / DMODEL) - mu * mu;
    const float inv = rsqrtf(var + 1e-5f);
    float4 y;
    y.x = (x0 - mu) * inv; y.y = (x1 - mu) * inv;
    y.z = (x2 - mu) * inv; y.w = (x3 - mu) * inv;
    *(float4*)(out + base) = y;
}

extern "C" void kernel_launch(void* const* d_in, const int* in_sizes, int n_in,
                              void* d_out, int out_size, void* d_ws, size_t ws_size,
                              hipStream_t stream)
{
    const float* inQ = (const float*)d_in[0];
    const float* inK = (const float*)d_in[1];
    const float* inV = (const float*)d_in[2];
    const int*   msk = (const int*)d_in[3];
    const float* WQ  = (const float*)d_in[4];
    const float* WK  = (const float*)d_in[5];
    const float* WV  = (const float*)d_in[6];
    const float* Wfc = (const float*)d_in[7];

    float* out_ln   = (float*)d_out;
    float* out_attn = out_ln + (size_t)NB * SS * DMODEL;

    // workspace carve (56 MB total): Qp 8M | Kp 8M | Vt 8M | ctx 16M | O 16M
    char* w = (char*)d_ws;
    bf16*  Qp   = (bf16*)(w);
    bf16*  Kp   = (bf16*)(w + (size_t)8  * 1024 * 1024);
    bf16*  Vt   = (bf16*)(w + (size_t)16 * 1024 * 1024);
    float* ctx  = (float*)(w + (size_t)24 * 1024 * 1024);
    float* Obuf = (float*)(w + (size_t)40 * 1024 * 1024);

    dim3 blk(256);
    dim3 gp(DMODEL / 64, (NB * SS) / 64);
    gemm_xwt<<<gp, blk, 0, stream>>>(inQ, WQ, (void*)Qp, 0);
    gemm_xwt<<<gp, blk, 0, stream>>>(inK, WK, (void*)Kp, 0);
    gemm_xwt<<<gp, blk, 0, stream>>>(inV, WV, (void*)Vt, 1);
    attn_fused<<<dim3(SS / 16, NH, NB), blk, 0, stream>>>(Qp, Kp, Vt, msk, out_attn, ctx);
    gemm_xwt<<<gp, blk, 0, stream>>>(ctx, Wfc, (void*)Obuf, 2);
    ln_resid<<<NB * SS, blk, 0, stream>>>(Obuf, inQ, out_ln);
}